// Round 3
// baseline (231.713 us; speedup 1.0000x reference)
//
#include <hip/hip_runtime.h>
#include <hip/hip_bf16.h>

// Problem constants: B=32, S=512, D=256, H=8, DH=32
#define SCALE_QK 0.17677669529663687f  // 1/sqrt(32)

typedef __attribute__((ext_vector_type(8))) short short8;  // 8 bf16 (4 VGPRs)
typedef __attribute__((ext_vector_type(4))) float f32x4;

__device__ __forceinline__ ushort f2bf(float f) {  // fp32 -> bf16 RNE
  unsigned u = __float_as_uint(f);
  return (ushort)((u + 0x7FFF + ((u >> 16) & 1)) >> 16);
}

// DPP lane-move within rows of 16 (our reduction groups are exactly DPP rows).
template <int CTRL>
__device__ __forceinline__ float dpp_movf(float x) {
  return __int_as_float(
      __builtin_amdgcn_update_dpp(0, __float_as_int(x), CTRL, 0xF, 0xF, true));
}
__device__ __forceinline__ float dpp_sum16(float x) {
  x += dpp_movf<0xB1>(x);
  x += dpp_movf<0x4E>(x);
  x += dpp_movf<0x141>(x);
  x += dpp_movf<0x140>(x);
  return x;
}
__device__ __forceinline__ float dpp_max16(float x) {
  x = fmaxf(x, dpp_movf<0xB1>(x));
  x = fmaxf(x, dpp_movf<0x4E>(x));
  x = fmaxf(x, dpp_movf<0x141>(x));
  x = fmaxf(x, dpp_movf<0x140>(x));
  return x;
}

// Merged prep: blocks [0,4224): convert x/Wq/Wk to bf16 (one float4/thread).
// Blocks [4224,4480): Wvo[e][m] = sum_d Wo[e][d]*Wv[d][m] (bf16), bvo = Wo.bv+bo.
__global__ __launch_bounds__(256) void prep(
    const float *__restrict__ x, const float *__restrict__ w0,
    const float *__restrict__ w1, const float *__restrict__ Wo,
    const float *__restrict__ Wv, const float *__restrict__ bv,
    const float *__restrict__ bo, ushort *__restrict__ xbf,
    ushort *__restrict__ wbf, ushort *__restrict__ wvo,
    float *__restrict__ bvo) {
  if (blockIdx.x < 4224) {
    const long i = (long)blockIdx.x * 256 + threadIdx.x;
    const long NX4 = 16384L * 256 / 4;  // 1048576
    const float *src;
    ushort4 *dst;
    long k;
    if (i < NX4) {
      src = x; k = i; dst = (ushort4 *)xbf;
    } else {
      const long j = i - NX4;  // [0, 32768)
      const int which = (int)(j >> 14);
      k = j & 16383;
      src = which == 0 ? w0 : w1;
      dst = (ushort4 *)(wbf + which * 65536L);
    }
    const float4 v = ((const float4 *)src)[k];
    ushort4 o;
    o.x = f2bf(v.x); o.y = f2bf(v.y); o.z = f2bf(v.z); o.w = f2bf(v.w);
    dst[k] = o;
  } else {
    const int e = blockIdx.x - 4224, m = threadIdx.x;
    float acc = 0.f;
    for (int d = 0; d < 256; ++d) acc += Wo[e * 256 + d] * Wv[d * 256 + m];
    wvo[e * 256 + m] = f2bf(acc);
    if (m == 0) {
      float s = 0.f;
      for (int d = 0; d < 256; ++d) s += Wo[e * 256 + d] * bv[d];
      bvo[e] = s + bo[e];
    }
  }
}

// 128-row x (16*NJ)-col NT bf16 MFMA tile body, K=256. Each wave owns two
// 16-row Y-tiles (iA, iA+64) x NJ 16-col X-tiles: 2+NJ loads -> 2*NJ MFMA
// per k-step.
// MODE 1: combined Q|K projection, cols<256 -> Q (scaled), else K.
// MODE 2: uT chunked layout [b][t>>5][e][t&31] bf16, + bias per e-row.
template <int NJ, int MODE>
__device__ __forceinline__ void gemm_body(
    const ushort *__restrict__ Y, const ushort *__restrict__ X,
    const float *__restrict__ bA, const float *__restrict__ bB,
    ushort *__restrict__ C0, ushort *__restrict__ C1, int iA, int j0, int b,
    int quad, int l15) {
  const ushort *xr[NJ];
#pragma unroll
  for (int nt = 0; nt < NJ; ++nt)
    xr[nt] = X + (long)(j0 + 16 * nt + l15) * 256 + quad * 8;
  const ushort *yrA = Y + (long)iA * 256 + quad * 8;

  f32x4 acc[2][NJ] = {};
#pragma unroll 1
  for (int ks = 0; ks < 256; ks += 32) {
    const short8 ya = *(const short8 *)(yrA + ks);
    const short8 yb = *(const short8 *)(yrA + 64 * 256 + ks);
#pragma unroll
    for (int nt = 0; nt < NJ; ++nt) {
      const short8 xf = *(const short8 *)(xr[nt] + ks);
      acc[0][nt] = __builtin_amdgcn_mfma_f32_16x16x32_bf16(xf, ya, acc[0][nt], 0, 0, 0);
      acc[1][nt] = __builtin_amdgcn_mfma_f32_16x16x32_bf16(xf, yb, acc[1][nt], 0, 0, 0);
    }
  }
#pragma unroll
  for (int side = 0; side < 2; ++side) {
    const int iLoc = iA + 64 * side;
#pragma unroll
    for (int nt = 0; nt < NJ; ++nt) {
      const int col0 = j0 + 16 * nt + 4 * quad;
      const f32x4 a = acc[side][nt];
      if (MODE == 1) {
        const int cq = col0 & 255;
        const float4 bs = *(const float4 *)((col0 < 256 ? bA : bB) + cq);
        const float scl = col0 < 256 ? SCALE_QK : 1.0f;
        ushort *base = col0 < 256 ? C0 : C1;
        const int bb = iLoc >> 9, s = iLoc & 511;
        const int h = cq >> 5, e = cq & 31;
        ushort4 st;
        st.x = f2bf((a[0] + bs.x) * scl);
        st.y = f2bf((a[1] + bs.y) * scl);
        st.z = f2bf((a[2] + bs.z) * scl);
        st.w = f2bf((a[3] + bs.w) * scl);
        *(ushort4 *)(base + (((long)(bb << 3) + h) * 512 + s) * 32 + e) = st;
      } else {
        const float bd = bA[iLoc];
        ushort4 st;
        st.x = f2bf(a[0] + bd); st.y = f2bf(a[1] + bd);
        st.z = f2bf(a[2] + bd); st.w = f2bf(a[3] + bd);
        *(ushort4 *)(C0 + ((long)b * 16 + (col0 >> 5)) * 8192 + iLoc * 32 +
                     (col0 & 31)) = st;
      }
    }
  }
}

// Both projection GEMMs in one launch. XCD co-location: blocks sharing the
// same Y-panel (same bx / same batch) are placed at gid stride 128 / 32
// (both ≡ 0 mod 8) so they land on the SAME XCD's L2 -> xbf panels fetched
// once per XCD instead of 4x through L3.
__global__ __launch_bounds__(256, 4) void gemm_all(
    const ushort *__restrict__ xbf, const ushort *__restrict__ wqk,
    const ushort *__restrict__ wvo, const float *__restrict__ bq,
    const float *__restrict__ bk, const float *__restrict__ bvo,
    ushort *__restrict__ qbf, ushort *__restrict__ kbf,
    ushort *__restrict__ uT) {
  const int tid = threadIdx.x;
  const int w = tid >> 6, lane = tid & 63;
  const int quad = lane >> 4, l15 = lane & 15;
  const int gid = blockIdx.x;
  if (gid < 512) {
    const int bx = gid & 127, by = gid >> 7;  // same-bx -> stride 128 -> same XCD
    const int iA = bx * 128 + w * 16 + l15;
    gemm_body<8, 1>(xbf, wqk, bq, bk, qbf, kbf, iA, by * 128, 0, quad, l15);
  } else {
    const int id2 = gid - 512;
    const int b = id2 & 31;                   // same-b -> stride 32 -> same XCD
    const int bx = (id2 >> 5) & 1, by = id2 >> 6;
    const int iA = bx * 128 + w * 16 + l15;
    gemm_body<4, 2>(wvo, xbf + (long)b * 131072, bvo, nullptr, uT, nullptr,
                    iA, by * 64, b, quad, l15);
  }
}

// Fused scores (MFMA bf16) + diag-mask + sparsemax + head-average + out-GEMM.
// New this round: z[] is no longer kept live through the solve — the score
// tile is already in LDS, so the scan / slow path / avgacc update re-read it
// (with the diag mask re-applied; bitwise-identical math). This drops ~32
// live VGPRs and, with __launch_bounds__(256,3), eliminates the scratch
// spills that round-2 counters implied (VGPR_Count=88 vs ~115 live).
__global__ __launch_bounds__(256, 3) void attn_sparsemax_fused(
    const ushort *__restrict__ Q, const ushort *__restrict__ K,
    const ushort *__restrict__ U, float *__restrict__ avg,
    float *__restrict__ out) {
  __shared__ f32x4 sc[16 * 128];  // 32 KB score tile; reused as bf16 p-tile
  const int tid = threadIdx.x;
  const int w = tid >> 6, lane = tid & 63;
  const int quad = lane >> 4, l15 = lane & 15;
  const int id = blockIdx.x;
  const int b = (id & 7) | (((id >> 3) & 3) << 3);  // batch -> XCD id&7
  const int s0 = (id >> 5) * 16;
  const int myrow = 4 * w + quad;
  const int sglob = s0 + myrow;
  // my solve-row LDS base: chunk c lives at rdbase + 16*c (f32x4 units)
  const int rdbase = myrow * 128 + (l15 ^ (myrow & 7));

  const ushort *qb = Q + ((long)(b << 3) * 512 + s0) * 32 + l15 * 32 + quad * 8;
  const ushort *kb =
      K + (long)(b << 3) * 512 * 32 + (w * 128 + l15) * 32 + quad * 8;
  short8 bq = *(const short8 *)qb;  // head 0 fragments
  short8 ak[8];
#pragma unroll
  for (int jl = 0; jl < 8; ++jl) ak[jl] = *(const short8 *)(kb + jl * 512);

  float avgacc[8][4] = {};
#pragma unroll 1
  for (int h = 0; h < 8; ++h) {
    f32x4 acc[8];
    __builtin_amdgcn_s_setprio(1);
#pragma unroll
    for (int jl = 0; jl < 8; ++jl)
      acc[jl] = __builtin_amdgcn_mfma_f32_16x16x32_bf16(
          ak[jl], bq, (f32x4){0.f, 0.f, 0.f, 0.f}, 0, 0, 0);
    __builtin_amdgcn_s_setprio(0);
    __syncthreads();
#pragma unroll
    for (int jl = 0; jl < 8; ++jl) {
      const int ch = 32 * w + 4 * jl + quad;
      sc[l15 * 128 + (ch ^ (l15 & 7))] = acc[jl];
    }
    __syncthreads();
    // prefetch next head's fragments; latency hides under the solve below
    if (h < 7) {
      bq = *(const short8 *)(qb + (h + 1) * 16384);
#pragma unroll
      for (int jl = 0; jl < 8; ++jl)
        ak[jl] = *(const short8 *)(kb + (h + 1) * 16384 + jl * 512);
    }
    // top-3 scan over LDS: q0 >= q1 >= q2 of this row's 32 values (masked)
    float q0 = -3e38f, q1 = -3e38f, q2 = -3e38f;
#pragma unroll
    for (int c = 0; c < 8; ++c) {
      f32x4 v = sc[rdbase + 16 * c];
#pragma unroll
      for (int r = 0; r < 4; ++r) {
        const float vv = (64 * c + 4 * l15 + r == sglob) ? -1e30f : v[r];
        const float t1 = fminf(q0, vv);
        q0 = fmaxf(q0, vv);
        const float t2 = fminf(q1, t1);
        q1 = fmaxf(q1, t1);
        q2 = fmaxf(q2, t2);
      }
    }
    const float M = dpp_max16(q0);
    const float thr = M - 1.0f;
    float tau = thr;
    float cOld = -1.f;
    if (__any(q2 > thr)) {
      // slow path: some lane holds >=3 candidates — full scan from LDS (rare)
#pragma unroll 1
      for (int it = 0; it < 32; ++it) {
        float s = 0.f, c = 0.f;
#pragma unroll
        for (int cc = 0; cc < 8; ++cc) {
          const f32x4 v = sc[rdbase + 16 * cc];
#pragma unroll
          for (int r = 0; r < 4; ++r) {
            const float vv = (64 * cc + 4 * l15 + r == sglob) ? -1e30f : v[r];
            const bool p = vv > tau;
            s += p ? vv : 0.f;
            c += p ? 1.f : 0.f;
          }
        }
        s = dpp_sum16(s);
        c = dpp_sum16(c);
        const bool stable = (c == cOld);
        if (__all(stable)) break;
        if (!stable) {
          tau = (s - 1.f) / c;
          cOld = c;
        }
      }
    } else {
      // fast path: candidates per lane are within {q0,q1}; tau >= thr is
      // monotone so elements <= thr can never enter the support.
#pragma unroll 1
      for (int it = 0; it < 32; ++it) {
        const bool p0 = q0 > tau, p1 = q1 > tau;
        float s = (p0 ? q0 : 0.f) + (p1 ? q1 : 0.f);
        float c = (p0 ? 1.f : 0.f) + (p1 ? 1.f : 0.f);
        s = dpp_sum16(s);
        c = dpp_sum16(c);
        const bool stable = (c == cOld);
        if (__all(stable)) break;
        if (!stable) {
          tau = (s - 1.f) / c;
          cOld = c;
        }
      }
    }
    // avgacc update: re-read + re-mask from LDS
#pragma unroll
    for (int c = 0; c < 8; ++c) {
      const f32x4 v = sc[rdbase + 16 * c];
#pragma unroll
      for (int r = 0; r < 4; ++r) {
        const float vv = (64 * c + 4 * l15 + r == sglob) ? -1e30f : v[r];
        avgacc[c][r] += fmaxf(vv - tau, 0.f);
      }
    }
  }
  // avg write (fp32, required output) + bf16 p-tile into reused LDS.
  __syncthreads();  // all waves done reading sc for head 7
  ushort *pl = (ushort *)sc;
  float *dst = avg + ((b * 512 + sglob) << 9) + 4 * l15;
#pragma unroll
  for (int c = 0; c < 8; ++c) {
    float4 o;
    o.x = avgacc[c][0] * 0.125f;
    o.y = avgacc[c][1] * 0.125f;
    o.z = avgacc[c][2] * 0.125f;
    o.w = avgacc[c][3] * 0.125f;
    *(float4 *)(dst + 64 * c) = o;
    ushort4 pv;
    pv.x = f2bf(o.x); pv.y = f2bf(o.y); pv.z = f2bf(o.z); pv.w = f2bf(o.w);
    // row myrow, cols 64c+4*l15..+3; XOR-swizzle bits 4..6 by row (T2)
    *(ushort4 *)((char *)pl +
                 ((myrow * 1024 + 128 * c + 8 * l15) ^ ((myrow & 7) << 4))) = pv;
  }
  __syncthreads();
  // fused out = avg . u : wave w covers e in [64w, 64w+64), all 16 s-rows.
  // uT chunk layout: [b][t>>5][e][t&31] -> each uf wave-load = 1KB contiguous.
  const ushort *ub = U + (long)b * 131072 + (64 * w + l15) * 32 + quad * 8;
  f32x4 oacc[4] = {{0.f, 0.f, 0.f, 0.f},
                   {0.f, 0.f, 0.f, 0.f},
                   {0.f, 0.f, 0.f, 0.f},
                   {0.f, 0.f, 0.f, 0.f}};
#pragma unroll
  for (int ks = 0; ks < 16; ++ks) {
    const short8 pf = *(const short8 *)(
        (char *)pl + (l15 * 1024 + ((ks * 64 + quad * 16) ^ ((l15 & 7) << 4))));
    __builtin_amdgcn_s_setprio(1);
#pragma unroll
    for (int nt = 0; nt < 4; ++nt) {
      const short8 uf = *(const short8 *)(ub + (long)ks * 8192 + nt * 512);
      oacc[nt] = __builtin_amdgcn_mfma_f32_16x16x32_bf16(uf, pf, oacc[nt], 0, 0, 0);
    }
    __builtin_amdgcn_s_setprio(0);
  }
  float *ob = out + ((long)b * 512 + s0 + l15) * 256 + 64 * w + 4 * quad;
#pragma unroll
  for (int nt = 0; nt < 4; ++nt) {
    float4 st;
    st.x = oacc[nt][0]; st.y = oacc[nt][1];
    st.z = oacc[nt][2]; st.w = oacc[nt][3];
    *(float4 *)(ob + 16 * nt) = st;
  }
}

extern "C" void kernel_launch(void* const* d_in, const int* in_sizes, int n_in,
                              void* d_out, int out_size, void* d_ws, size_t ws_size,
                              hipStream_t stream) {
  const float *x  = (const float *)d_in[0];
  const float *Wq = (const float *)d_in[1];
  const float *bq = (const float *)d_in[2];
  const float *Wk = (const float *)d_in[3];
  const float *bk = (const float *)d_in[4];
  const float *Wv = (const float *)d_in[5];
  const float *bv = (const float *)d_in[6];
  const float *Wo = (const float *)d_in[7];
  const float *bo = (const float *)d_in[8];

  float *out = (float *)d_out;                 // [B,S,D]
  float *avg = out + 32 * 512 * 256;           // [B,S,S] fp32

  // ws (ushort units): xbf | qbf | kbf | uT | wq,wk,wvo | bvo  ~= 33.9 MB
  ushort *ws16 = (ushort *)d_ws;
  ushort *xbf = ws16;                          // [16384][256] bf16
  ushort *qbf = ws16 + 4194304;                // [B,H,S,32] bf16 (pre-scaled)
  ushort *kbf = ws16 + 8388608;                // [B,H,S,32] bf16
  ushort *uT  = ws16 + 12582912;               // [B][16 tc][256 e][32 t] bf16
  ushort *wbf = ws16 + 16777216;               // Wq|Wk|Wvo bf16, 65536 each
  float  *bvo = (float *)(ws16 + 16973824);    // [256] fp32

  prep<<<dim3(4480), dim3(256), 0, stream>>>(x, Wq, Wk, Wo, Wv, bv, bo, xbf,
                                             wbf, wbf + 131072, bvo);
  gemm_all<<<dim3(1024), dim3(256), 0, stream>>>(xbf, wbf, wbf + 131072, bq,
                                                 bk, bvo, qbf, kbf, uT);
  attn_sparsemax_fused<<<dim3(1024), dim3(256), 0, stream>>>(qbf, kbf, uT,
                                                             avg, out);
}

// Round 4
// 217.246 us; speedup vs baseline: 1.0666x; 1.0666x over previous
//
#include <hip/hip_runtime.h>
#include <hip/hip_bf16.h>

// Problem constants: B=32, S=512, D=256, H=8, DH=32
#define SCALE_QK 0.17677669529663687f  // 1/sqrt(32)

typedef __attribute__((ext_vector_type(8))) short short8;  // 8 bf16 (4 VGPRs)
typedef __attribute__((ext_vector_type(4))) float f32x4;

__device__ __forceinline__ ushort f2bf(float f) {  // fp32 -> bf16 RNE
  unsigned u = __float_as_uint(f);
  return (ushort)((u + 0x7FFF + ((u >> 16) & 1)) >> 16);
}

// DPP lane-move within rows of 16 (our reduction groups are exactly DPP rows).
template <int CTRL>
__device__ __forceinline__ float dpp_movf(float x) {
  return __int_as_float(
      __builtin_amdgcn_update_dpp(0, __float_as_int(x), CTRL, 0xF, 0xF, true));
}
__device__ __forceinline__ float dpp_sum16(float x) {
  x += dpp_movf<0xB1>(x);
  x += dpp_movf<0x4E>(x);
  x += dpp_movf<0x141>(x);
  x += dpp_movf<0x140>(x);
  return x;
}
__device__ __forceinline__ float dpp_max16(float x) {
  x = fmaxf(x, dpp_movf<0xB1>(x));
  x = fmaxf(x, dpp_movf<0x4E>(x));
  x = fmaxf(x, dpp_movf<0x141>(x));
  x = fmaxf(x, dpp_movf<0x140>(x));
  return x;
}

// Merged prep: blocks [0,4224): convert x/Wq/Wk to bf16 (one float4/thread).
// Blocks [4224,4480): Wvo[e][m] = sum_d Wo[e][d]*Wv[d][m] (bf16), bvo = Wo.bv+bo.
// make_wvo part now: d-loop unrolled x8 with 4 independent partial sums
// (was a fully latency-exposed 256-iter chain at 1 wave/SIMD ≈ 30 µs), and
// bvo is a parallel block-reduce (was a single-thread 256-iter chain).
__global__ __launch_bounds__(256) void prep(
    const float *__restrict__ x, const float *__restrict__ w0,
    const float *__restrict__ w1, const float *__restrict__ Wo,
    const float *__restrict__ Wv, const float *__restrict__ bv,
    const float *__restrict__ bo, ushort *__restrict__ xbf,
    ushort *__restrict__ wbf, ushort *__restrict__ wvo,
    float *__restrict__ bvo) {
  __shared__ float tmp[256];
  if (blockIdx.x < 4224) {
    const long i = (long)blockIdx.x * 256 + threadIdx.x;
    const long NX4 = 16384L * 256 / 4;  // 1048576
    const float *src;
    ushort4 *dst;
    long k;
    if (i < NX4) {
      src = x; k = i; dst = (ushort4 *)xbf;
    } else {
      const long j = i - NX4;  // [0, 32768)
      const int which = (int)(j >> 14);
      k = j & 16383;
      src = which == 0 ? w0 : w1;
      dst = (ushort4 *)(wbf + which * 65536L);
    }
    const float4 v = ((const float4 *)src)[k];
    ushort4 o;
    o.x = f2bf(v.x); o.y = f2bf(v.y); o.z = f2bf(v.z); o.w = f2bf(v.w);
    dst[k] = o;
  } else {
    const int e = blockIdx.x - 4224, m = threadIdx.x;
    float a0 = 0.f, a1 = 0.f, a2 = 0.f, a3 = 0.f;
#pragma unroll 4
    for (int d = 0; d < 256; d += 8) {
      const float4 wo0 = *(const float4 *)(Wo + e * 256 + d);      // uniform
      const float4 wo1 = *(const float4 *)(Wo + e * 256 + d + 4);  // uniform
      a0 += wo0.x * Wv[(d + 0) * 256 + m];
      a1 += wo0.y * Wv[(d + 1) * 256 + m];
      a2 += wo0.z * Wv[(d + 2) * 256 + m];
      a3 += wo0.w * Wv[(d + 3) * 256 + m];
      a0 += wo1.x * Wv[(d + 4) * 256 + m];
      a1 += wo1.y * Wv[(d + 5) * 256 + m];
      a2 += wo1.z * Wv[(d + 6) * 256 + m];
      a3 += wo1.w * Wv[(d + 7) * 256 + m];
    }
    wvo[e * 256 + m] = f2bf((a0 + a1) + (a2 + a3));
    // bvo[e] = sum_d Wo[e][d]*bv[d] + bo[e], block-parallel reduction
    tmp[m] = Wo[e * 256 + m] * bv[m];
    __syncthreads();
    if (m < 64) {
      float q = tmp[m] + tmp[m + 64] + tmp[m + 128] + tmp[m + 192];
      q = dpp_sum16(q);
      const float r =
          __shfl(q, 0) + __shfl(q, 16) + __shfl(q, 32) + __shfl(q, 48);
      if (m == 0) bvo[e] = r + bo[e];
    }
  }
}

// 128-row x (16*NJ)-col NT bf16 MFMA tile body, K=256. Each wave owns two
// 16-row Y-tiles (iA, iA+64) x NJ 16-col X-tiles: 2+NJ loads -> 2*NJ MFMA
// per k-step.
// MODE 1: combined Q|K projection, cols<256 -> Q (scaled), else K.
// MODE 2: uT chunked layout [b][t>>5][e][t&31] bf16, + bias per e-row.
template <int NJ, int MODE>
__device__ __forceinline__ void gemm_body(
    const ushort *__restrict__ Y, const ushort *__restrict__ X,
    const float *__restrict__ bA, const float *__restrict__ bB,
    ushort *__restrict__ C0, ushort *__restrict__ C1, int iA, int j0, int b,
    int quad, int l15) {
  const ushort *xr[NJ];
#pragma unroll
  for (int nt = 0; nt < NJ; ++nt)
    xr[nt] = X + (long)(j0 + 16 * nt + l15) * 256 + quad * 8;
  const ushort *yrA = Y + (long)iA * 256 + quad * 8;

  f32x4 acc[2][NJ] = {};
#pragma unroll 1
  for (int ks = 0; ks < 256; ks += 32) {
    const short8 ya = *(const short8 *)(yrA + ks);
    const short8 yb = *(const short8 *)(yrA + 64 * 256 + ks);
#pragma unroll
    for (int nt = 0; nt < NJ; ++nt) {
      const short8 xf = *(const short8 *)(xr[nt] + ks);
      acc[0][nt] = __builtin_amdgcn_mfma_f32_16x16x32_bf16(xf, ya, acc[0][nt], 0, 0, 0);
      acc[1][nt] = __builtin_amdgcn_mfma_f32_16x16x32_bf16(xf, yb, acc[1][nt], 0, 0, 0);
    }
  }
#pragma unroll
  for (int side = 0; side < 2; ++side) {
    const int iLoc = iA + 64 * side;
#pragma unroll
    for (int nt = 0; nt < NJ; ++nt) {
      const int col0 = j0 + 16 * nt + 4 * quad;
      const f32x4 a = acc[side][nt];
      if (MODE == 1) {
        const int cq = col0 & 255;
        const float4 bs = *(const float4 *)((col0 < 256 ? bA : bB) + cq);
        const float scl = col0 < 256 ? SCALE_QK : 1.0f;
        ushort *base = col0 < 256 ? C0 : C1;
        const int bb = iLoc >> 9, s = iLoc & 511;
        const int h = cq >> 5, e = cq & 31;
        ushort4 st;
        st.x = f2bf((a[0] + bs.x) * scl);
        st.y = f2bf((a[1] + bs.y) * scl);
        st.z = f2bf((a[2] + bs.z) * scl);
        st.w = f2bf((a[3] + bs.w) * scl);
        *(ushort4 *)(base + (((long)(bb << 3) + h) * 512 + s) * 32 + e) = st;
      } else {
        const float bd = bA[iLoc];
        ushort4 st;
        st.x = f2bf(a[0] + bd); st.y = f2bf(a[1] + bd);
        st.z = f2bf(a[2] + bd); st.w = f2bf(a[3] + bd);
        *(ushort4 *)(C0 + ((long)b * 16 + (col0 >> 5)) * 8192 + iLoc * 32 +
                     (col0 & 31)) = st;
      }
    }
  }
}

// Both projection GEMMs in one launch. XCD co-location: blocks sharing the
// same Y-panel (same bx / same batch) are placed at gid stride 128 / 32
// (both ≡ 0 mod 8) so they land on the SAME XCD's L2.
__global__ __launch_bounds__(256) void gemm_all(
    const ushort *__restrict__ xbf, const ushort *__restrict__ wqk,
    const ushort *__restrict__ wvo, const float *__restrict__ bq,
    const float *__restrict__ bk, const float *__restrict__ bvo,
    ushort *__restrict__ qbf, ushort *__restrict__ kbf,
    ushort *__restrict__ uT) {
  const int tid = threadIdx.x;
  const int w = tid >> 6, lane = tid & 63;
  const int quad = lane >> 4, l15 = lane & 15;
  const int gid = blockIdx.x;
  if (gid < 512) {
    const int bx = gid & 127, by = gid >> 7;  // same-bx -> stride 128 -> same XCD
    const int iA = bx * 128 + w * 16 + l15;
    gemm_body<8, 1>(xbf, wqk, bq, bk, qbf, kbf, iA, by * 128, 0, quad, l15);
  } else {
    const int id2 = gid - 512;
    const int b = id2 & 31;                   // same-b -> stride 32 -> same XCD
    const int bx = (id2 >> 5) & 1, by = id2 >> 6;
    const int iA = bx * 128 + w * 16 + l15;
    gemm_body<4, 2>(wvo, xbf + (long)b * 131072, bvo, nullptr, uT, nullptr,
                    iA, by * 64, b, quad, l15);
  }
}

// Fused scores (MFMA bf16) + diag-mask + sparsemax + head-average + out-GEMM.
// Round-4 structure: z back in registers (round-2's faster variant), and the
// diagonal is masked ONCE in LDS at write time (a single ds_write_b32 of
// -1e30 by the owning wave) — all per-element ==sglob compares are gone from
// the scan / slow path / avgacc passes (~200 VALU/head removed).
__global__ __launch_bounds__(256) void attn_sparsemax_fused(
    const ushort *__restrict__ Q, const ushort *__restrict__ K,
    const ushort *__restrict__ U, float *__restrict__ avg,
    float *__restrict__ out) {
  __shared__ f32x4 sc[16 * 128];  // 32 KB score tile; reused as bf16 p-tile
  const int tid = threadIdx.x;
  const int w = tid >> 6, lane = tid & 63;
  const int quad = lane >> 4, l15 = lane & 15;
  const int id = blockIdx.x;
  const int b = (id & 7) | (((id >> 3) & 3) << 3);  // batch -> XCD id&7
  const int s0 = (id >> 5) * 16;
  const int myrow = 4 * w + quad;
  const int sglob = s0 + myrow;
  const int rdbase = myrow * 128 + (l15 ^ (myrow & 7));
  // diag poke (one lane per row): wave (s0>>7), quad==0, lane l15 pokes
  // row l15's diagonal element (col s0+l15) after the tile writes.
  const int dcol = s0 + l15;
  const int pokeIdx = 4 * (l15 * 128 + ((dcol >> 2) ^ (l15 & 7))) + (dcol & 3);
  const bool poker = (w == (s0 >> 7)) && (quad == 0);

  const ushort *qb = Q + ((long)(b << 3) * 512 + s0) * 32 + l15 * 32 + quad * 8;
  const ushort *kb =
      K + (long)(b << 3) * 512 * 32 + (w * 128 + l15) * 32 + quad * 8;
  short8 bq = *(const short8 *)qb;  // head 0 fragments
  short8 ak[8];
#pragma unroll
  for (int jl = 0; jl < 8; ++jl) ak[jl] = *(const short8 *)(kb + jl * 512);

  float avgacc[8][4] = {};
#pragma unroll 1
  for (int h = 0; h < 8; ++h) {
    f32x4 acc[8];
    __builtin_amdgcn_s_setprio(1);
#pragma unroll
    for (int jl = 0; jl < 8; ++jl)
      acc[jl] = __builtin_amdgcn_mfma_f32_16x16x32_bf16(
          ak[jl], bq, (f32x4){0.f, 0.f, 0.f, 0.f}, 0, 0, 0);
    __builtin_amdgcn_s_setprio(0);
    __syncthreads();
#pragma unroll
    for (int jl = 0; jl < 8; ++jl) {
      const int ch = 32 * w + 4 * jl + quad;
      sc[l15 * 128 + (ch ^ (l15 & 7))] = acc[jl];
    }
    if (poker) ((float *)sc)[pokeIdx] = -1e30f;  // after writes: same-wave DS order
    __syncthreads();
    // prefetch next head's fragments; latency hides under the solve below
    if (h < 7) {
      bq = *(const short8 *)(qb + (h + 1) * 16384);
#pragma unroll
      for (int jl = 0; jl < 8; ++jl)
        ak[jl] = *(const short8 *)(kb + (h + 1) * 16384 + jl * 512);
    }
    f32x4 z[8];
#pragma unroll
    for (int c = 0; c < 8; ++c) z[c] = sc[rdbase + 16 * c];
    // top-3 scan: q0 >= q1 >= q2 of this lane's 32 values (diag pre-masked)
    float q0 = -3e38f, q1 = -3e38f, q2 = -3e38f;
#pragma unroll
    for (int c = 0; c < 8; ++c)
#pragma unroll
      for (int r = 0; r < 4; ++r) {
        const float v = z[c][r];
        const float t1 = fminf(q0, v);
        q0 = fmaxf(q0, v);
        const float t2 = fminf(q1, t1);
        q1 = fmaxf(q1, t1);
        q2 = fmaxf(q2, t2);
      }
    const float M = dpp_max16(q0);
    const float thr = M - 1.0f;
    float tau = thr;
    float cOld = -1.f;
    if (__any(q2 > thr)) {
      // slow path: some lane holds >=3 candidates — full scan (rare)
#pragma unroll 1
      for (int it = 0; it < 32; ++it) {
        float s = 0.f, c = 0.f;
#pragma unroll
        for (int cc = 0; cc < 8; ++cc)
#pragma unroll
          for (int r = 0; r < 4; ++r) {
            const bool p = z[cc][r] > tau;
            s += p ? z[cc][r] : 0.f;
            c += p ? 1.f : 0.f;
          }
        s = dpp_sum16(s);
        c = dpp_sum16(c);
        const bool stable = (c == cOld);
        if (__all(stable)) break;
        if (!stable) {
          tau = (s - 1.f) / c;
          cOld = c;
        }
      }
    } else {
      // fast path: candidates per lane are within {q0,q1}; tau >= thr is
      // monotone so elements <= thr can never enter the support.
#pragma unroll 1
      for (int it = 0; it < 32; ++it) {
        const bool p0 = q0 > tau, p1 = q1 > tau;
        float s = (p0 ? q0 : 0.f) + (p1 ? q1 : 0.f);
        float c = (p0 ? 1.f : 0.f) + (p1 ? 1.f : 0.f);
        s = dpp_sum16(s);
        c = dpp_sum16(c);
        const bool stable = (c == cOld);
        if (__all(stable)) break;
        if (!stable) {
          tau = (s - 1.f) / c;
          cOld = c;
        }
      }
    }
#pragma unroll
    for (int c = 0; c < 8; ++c)
#pragma unroll
      for (int r = 0; r < 4; ++r)
        avgacc[c][r] += fmaxf(z[c][r] - tau, 0.f);
  }
  // avg write (fp32, required output) + bf16 p-tile into reused LDS.
  __syncthreads();  // all waves done reading sc for head 7
  ushort *pl = (ushort *)sc;
  float *dst = avg + ((b * 512 + sglob) << 9) + 4 * l15;
#pragma unroll
  for (int c = 0; c < 8; ++c) {
    float4 o;
    o.x = avgacc[c][0] * 0.125f;
    o.y = avgacc[c][1] * 0.125f;
    o.z = avgacc[c][2] * 0.125f;
    o.w = avgacc[c][3] * 0.125f;
    *(float4 *)(dst + 64 * c) = o;
    ushort4 pv;
    pv.x = f2bf(o.x); pv.y = f2bf(o.y); pv.z = f2bf(o.z); pv.w = f2bf(o.w);
    // row myrow, cols 64c+4*l15..+3; XOR-swizzle bits 4..6 by row (T2)
    *(ushort4 *)((char *)pl +
                 ((myrow * 1024 + 128 * c + 8 * l15) ^ ((myrow & 7) << 4))) = pv;
  }
  __syncthreads();
  // fused out = avg . u : wave w covers e in [64w, 64w+64), all 16 s-rows.
  // uT chunk layout: [b][t>>5][e][t&31] -> each uf wave-load = 1KB contiguous.
  const ushort *ub = U + (long)b * 131072 + (64 * w + l15) * 32 + quad * 8;
  f32x4 oacc[4] = {{0.f, 0.f, 0.f, 0.f},
                   {0.f, 0.f, 0.f, 0.f},
                   {0.f, 0.f, 0.f, 0.f},
                   {0.f, 0.f, 0.f, 0.f}};
#pragma unroll
  for (int ks = 0; ks < 16; ++ks) {
    const short8 pf = *(const short8 *)(
        (char *)pl + (l15 * 1024 + ((ks * 64 + quad * 16) ^ ((l15 & 7) << 4))));
    __builtin_amdgcn_s_setprio(1);
#pragma unroll
    for (int nt = 0; nt < 4; ++nt) {
      const short8 uf = *(const short8 *)(ub + (long)ks * 8192 + nt * 512);
      oacc[nt] = __builtin_amdgcn_mfma_f32_16x16x32_bf16(uf, pf, oacc[nt], 0, 0, 0);
    }
    __builtin_amdgcn_s_setprio(0);
  }
  float *ob = out + ((long)b * 512 + s0 + l15) * 256 + 64 * w + 4 * quad;
#pragma unroll
  for (int nt = 0; nt < 4; ++nt) {
    float4 st;
    st.x = oacc[nt][0]; st.y = oacc[nt][1];
    st.z = oacc[nt][2]; st.w = oacc[nt][3];
    *(float4 *)(ob + 16 * nt) = st;
  }
}

extern "C" void kernel_launch(void* const* d_in, const int* in_sizes, int n_in,
                              void* d_out, int out_size, void* d_ws, size_t ws_size,
                              hipStream_t stream) {
  const float *x  = (const float *)d_in[0];
  const float *Wq = (const float *)d_in[1];
  const float *bq = (const float *)d_in[2];
  const float *Wk = (const float *)d_in[3];
  const float *bk = (const float *)d_in[4];
  const float *Wv = (const float *)d_in[5];
  const float *bv = (const float *)d_in[6];
  const float *Wo = (const float *)d_in[7];
  const float *bo = (const float *)d_in[8];

  float *out = (float *)d_out;                 // [B,S,D]
  float *avg = out + 32 * 512 * 256;           // [B,S,S] fp32

  // ws (ushort units): xbf | qbf | kbf | uT | wq,wk,wvo | bvo  ~= 33.9 MB
  ushort *ws16 = (ushort *)d_ws;
  ushort *xbf = ws16;                          // [16384][256] bf16
  ushort *qbf = ws16 + 4194304;                // [B,H,S,32] bf16 (pre-scaled)
  ushort *kbf = ws16 + 8388608;                // [B,H,S,32] bf16
  ushort *uT  = ws16 + 12582912;               // [B][16 tc][256 e][32 t] bf16
  ushort *wbf = ws16 + 16777216;               // Wq|Wk|Wvo bf16, 65536 each
  float  *bvo = (float *)(ws16 + 16973824);    // [256] fp32

  prep<<<dim3(4480), dim3(256), 0, stream>>>(x, Wq, Wk, Wo, Wv, bv, bo, xbf,
                                             wbf, wbf + 131072, bvo);
  gemm_all<<<dim3(1024), dim3(256), 0, stream>>>(xbf, wbf, wbf + 131072, bq,
                                                 bk, bvo, qbf, kbf, uT);
  attn_sparsemax_fused<<<dim3(1024), dim3(256), 0, stream>>>(qbf, kbf, uT,
                                                             avg, out);
}

// Round 6
// 194.469 us; speedup vs baseline: 1.1915x; 1.1171x over previous
//
#include <hip/hip_runtime.h>
#include <hip/hip_bf16.h>

// Problem constants: B=32, S=512, D=256, H=8, DH=32
#define SCALE_QK 0.17677669529663687f  // 1/sqrt(32)

typedef __attribute__((ext_vector_type(8))) short short8;  // 8 bf16 (4 VGPRs)
typedef __attribute__((ext_vector_type(4))) float f32x4;

__device__ __forceinline__ ushort f2bf(float f) {  // fp32 -> bf16 RNE
  unsigned u = __float_as_uint(f);
  return (ushort)((u + 0x7FFF + ((u >> 16) & 1)) >> 16);
}

template <int CTRL>
__device__ __forceinline__ float dpp_movf(float x) {
  return __int_as_float(
      __builtin_amdgcn_update_dpp(0, __float_as_int(x), CTRL, 0xF, 0xF, true));
}
__device__ __forceinline__ float dpp_sum16(float x) {
  x += dpp_movf<0xB1>(x);
  x += dpp_movf<0x4E>(x);
  x += dpp_movf<0x141>(x);
  x += dpp_movf<0x140>(x);
  return x;
}
__device__ __forceinline__ float dpp_max16(float x) {
  x = fmaxf(x, dpp_movf<0xB1>(x));
  x = fmaxf(x, dpp_movf<0x4E>(x));
  x = fmaxf(x, dpp_movf<0x141>(x));
  x = fmaxf(x, dpp_movf<0x140>(x));
  return x;
}

// Exact merge of two sorted triples (A0>=A1>=A2), (B0>=B1>=B2) -> top-3 of
// union into A. Third-place needs A2/B2 only when one list supplies top-2.
#define MERGE3(A0, A1, A2, B0, B1, B2)                               \
  {                                                                  \
    const float m0_ = fmaxf(A0, B0), t_ = fminf(A0, B0);             \
    const float u_ = fmaxf(A1, B1), v_ = fminf(A1, B1);              \
    const float X_ = (A1 >= B0) ? A2 : ((B1 >= A0) ? B2 : -3e38f);   \
    A2 = fmaxf(fmaxf(v_, fminf(t_, u_)), X_);                        \
    A1 = fmaxf(t_, u_);                                              \
    A0 = m0_;                                                        \
  }

// ---------------------------------------------------------------------------
// Fragment-chunk layout ("frag"): element (row,k) of a [R][K] bf16 matrix at
//   chunk = (row>>4)*(K/32) + (k>>5)
//   off   = chunk*512 + ((k>>3)&3)*128 + (row&15)*8 + (k&7)       [ushorts]
// A wave fragment (16 rows x 32 k) is then ONE contiguous 1KB load at
//   base + chunk*512 + lane*8   (lane = quad*16 + l15).
// ---------------------------------------------------------------------------

// prep: blocks [0,2112): convert x|Wq|Wk to frag layout, one 1KB chunk/wave
// (contiguous 16B/lane writes). Blocks [2112,2368): Wvo = Wo.Wv (frag bf16),
// bvo = Wo.bv + bo (block-parallel reduce).
__global__ __launch_bounds__(256) void prep(
    const float *__restrict__ x, const float *__restrict__ w0,
    const float *__restrict__ w1, const float *__restrict__ Wo,
    const float *__restrict__ Wv, const float *__restrict__ bv,
    const float *__restrict__ bo, ushort *__restrict__ xbf,
    ushort *__restrict__ wbf, ushort *__restrict__ wvo,
    float *__restrict__ bvo) {
  __shared__ float tmp[256];
  const int tid = threadIdx.x;
  if (blockIdx.x < 2112) {
    const int w = tid >> 6, lane = tid & 63;
    const int quad = lane >> 4, l15 = lane & 15;
    const int chunk = blockIdx.x * 4 + w;  // [0, 8448)
    const int cc = chunk < 8192 ? chunk : chunk - 8192;
    const int rt = cc >> 3, kt = chunk & 7;
    const int row = rt * 16 + l15;
    const float *srcp;
    ushort *dstp;
    if (chunk < 8192) {
      srcp = x + (long)row * 256;
      dstp = xbf + (long)chunk * 512;
    } else {
      srcp = row < 256 ? w0 + (long)row * 256 : w1 + (long)(row - 256) * 256;
      dstp = wbf + (long)cc * 512;
    }
    const float4 v0 = *(const float4 *)(srcp + kt * 32 + quad * 8);
    const float4 v1 = *(const float4 *)(srcp + kt * 32 + quad * 8 + 4);
    short8 o = {(short)f2bf(v0.x), (short)f2bf(v0.y), (short)f2bf(v0.z),
                (short)f2bf(v0.w), (short)f2bf(v1.x), (short)f2bf(v1.y),
                (short)f2bf(v1.z), (short)f2bf(v1.w)};
    *(short8 *)(dstp + lane * 8) = o;
  } else {
    const int e = blockIdx.x - 2112, m = tid;
    float a0 = 0.f, a1 = 0.f, a2 = 0.f, a3 = 0.f;
#pragma unroll 4
    for (int d = 0; d < 256; d += 8) {
      const float4 wo0 = *(const float4 *)(Wo + e * 256 + d);      // uniform
      const float4 wo1 = *(const float4 *)(Wo + e * 256 + d + 4);  // uniform
      a0 += wo0.x * Wv[(d + 0) * 256 + m];
      a1 += wo0.y * Wv[(d + 1) * 256 + m];
      a2 += wo0.z * Wv[(d + 2) * 256 + m];
      a3 += wo0.w * Wv[(d + 3) * 256 + m];
      a0 += wo1.x * Wv[(d + 4) * 256 + m];
      a1 += wo1.y * Wv[(d + 5) * 256 + m];
      a2 += wo1.z * Wv[(d + 6) * 256 + m];
      a3 += wo1.w * Wv[(d + 7) * 256 + m];
    }
    const long off = ((long)(e >> 4) * 8 + (m >> 5)) * 512 +
                     ((m >> 3) & 3) * 128 + (e & 15) * 8 + (m & 7);
    wvo[off] = f2bf((a0 + a1) + (a2 + a3));
    tmp[m] = Wo[e * 256 + m] * bv[m];
    __syncthreads();
    if (m < 64) {
      float q = tmp[m] + tmp[m + 64] + tmp[m + 128] + tmp[m + 192];
      q = dpp_sum16(q);
      const float r =
          __shfl(q, 0) + __shfl(q, 16) + __shfl(q, 32) + __shfl(q, 48);
      if (m == 0) bvo[e] = r + bo[e];
    }
  }
}

// 128x(16*NJ) NT tile on frag operands, K=256 (8 kTiles). Every load is one
// contiguous 1KB wave-load; every store one contiguous wave-store.
// MODE 1: combined Q|K projection (frag out).  MODE 2: uT (frag out).
template <int NJ, int MODE>
__device__ __forceinline__ void gemm_body(
    const ushort *__restrict__ Yf, const ushort *__restrict__ Xf,
    const float *__restrict__ bA, const float *__restrict__ bB,
    ushort *__restrict__ C0, ushort *__restrict__ C1, int yrt, int xrt0,
    int bx, int by, int b, int w, int quad, int l15, int lane) {
  const ushort *yb0 = Yf + (long)yrt * 8 * 512 + lane * 8;
  const ushort *xb[NJ];
#pragma unroll
  for (int nt = 0; nt < NJ; ++nt)
    xb[nt] = Xf + (long)(xrt0 + nt) * 8 * 512 + lane * 8;

  f32x4 acc[2][NJ] = {};
#pragma unroll 1
  for (int kt = 0; kt < 8; ++kt) {
    const short8 ya = *(const short8 *)(yb0 + kt * 512);
    const short8 yc = *(const short8 *)(yb0 + 32 * 512 + kt * 512);
#pragma unroll
    for (int nt = 0; nt < NJ; ++nt) {
      const short8 xf = *(const short8 *)(xb[nt] + kt * 512);
      acc[0][nt] = __builtin_amdgcn_mfma_f32_16x16x32_bf16(xf, ya, acc[0][nt], 0, 0, 0);
      acc[1][nt] = __builtin_amdgcn_mfma_f32_16x16x32_bf16(xf, yc, acc[1][nt], 0, 0, 0);
    }
  }
#pragma unroll
  for (int side = 0; side < 2; ++side) {
#pragma unroll
    for (int nt = 0; nt < NJ; ++nt) {
      const int iLoc = bx * 128 + w * 16 + 64 * side + l15;
      const f32x4 a = acc[side][nt];
      if (MODE == 1) {
        const int col0 = by * 128 + 16 * nt + 4 * quad;
        const int cq = col0 & 255;
        const float4 bs = *(const float4 *)((col0 < 256 ? bA : bB) + cq);
        const float scl = col0 < 256 ? SCALE_QK : 1.0f;
        ushort *base = col0 < 256 ? C0 : C1;
        const int h = cq >> 5, e = cq & 31;
        // chunk = (b*8 + h)*32 + (s>>4), s = iLoc & 511   [R5 bug: used iLoc>>4]
        const long off =
            ((long)((iLoc >> 9) * 8 + h) * 32 + ((iLoc & 511) >> 4)) * 512 +
            ((e >> 3) & 3) * 128 + l15 * 8 + (e & 7);
        ushort4 st;
        st.x = f2bf((a[0] + bs.x) * scl);
        st.y = f2bf((a[1] + bs.y) * scl);
        st.z = f2bf((a[2] + bs.z) * scl);
        st.w = f2bf((a[3] + bs.w) * scl);
        *(ushort4 *)(base + off) = st;
      } else {
        const int col0 = by * 64 + 16 * nt + 4 * quad;
        const float bd = bA[iLoc];
        const long off = (long)b * 131072 +
                         ((long)(iLoc >> 4) * 16 + (col0 >> 5)) * 512 +
                         ((col0 >> 3) & 3) * 128 + l15 * 8 + (col0 & 7);
        ushort4 st;
        st.x = f2bf(a[0] + bd); st.y = f2bf(a[1] + bd);
        st.z = f2bf(a[2] + bd); st.w = f2bf(a[3] + bd);
        *(ushort4 *)(C0 + off) = st;
      }
    }
  }
}

// Both projection GEMMs, one launch; same-Y-panel blocks at gid stride 128/32
// (both == 0 mod 8) -> same XCD L2.
__global__ __launch_bounds__(256) void gemm_all(
    const ushort *__restrict__ xbf, const ushort *__restrict__ wqk,
    const ushort *__restrict__ wvo, const float *__restrict__ bq,
    const float *__restrict__ bk, const float *__restrict__ bvo,
    ushort *__restrict__ qbf, ushort *__restrict__ kbf,
    ushort *__restrict__ uT) {
  const int tid = threadIdx.x;
  const int w = tid >> 6, lane = tid & 63;
  const int quad = lane >> 4, l15 = lane & 15;
  const int gid = blockIdx.x;
  if (gid < 512) {
    const int bx = gid & 127, by = gid >> 7;
    gemm_body<8, 1>(xbf, wqk, bq, bk, qbf, kbf, bx * 8 + w, by * 8, bx, by, 0,
                    w, quad, l15, lane);
  } else {
    const int id2 = gid - 512;
    const int b = id2 & 31, bx = (id2 >> 5) & 1, by = id2 >> 6;
    gemm_body<4, 2>(wvo, xbf, bvo, nullptr, uT, nullptr, bx * 8 + w,
                    b * 32 + by * 4, bx, by, b, w, quad, l15, lane);
  }
}

// Fused scores + diag-poke + sparsemax (top-3 via 4 independent chains +
// exact triple-merge; fast path on (q0,q1)) + head-average + out-GEMM with
// LDS-staged contiguous out stores. All Q/K/U loads are contiguous frag loads.
__global__ __launch_bounds__(256, 4) void attn_sparsemax_fused(
    const ushort *__restrict__ Q, const ushort *__restrict__ K,
    const ushort *__restrict__ U, float *__restrict__ avg,
    float *__restrict__ out) {
  __shared__ f32x4 sc[16 * 128];  // 32 KB: scores; then p-tile | out-stage
  const int tid = threadIdx.x;
  const int w = tid >> 6, lane = tid & 63;
  const int quad = lane >> 4, l15 = lane & 15;
  const int id = blockIdx.x;
  const int b = (id & 7) | (((id >> 3) & 3) << 3);  // batch -> XCD id&7
  const int s0 = (id >> 5) * 16;
  const int myrow = 4 * w + quad;
  const int sglob = s0 + myrow;
  const int rdbase = myrow * 128 + (l15 ^ (myrow & 7));
  const int dcol = s0 + l15;
  const int pokeIdx = 4 * (l15 * 128 + ((dcol >> 2) ^ (l15 & 7))) + (dcol & 3);
  const bool poker = (w == (s0 >> 7)) && (quad == 0);

  // frag bases: per (b,h) block = 32 chunks x 512; head stride 16384.
  const ushort *qb = Q + ((long)(b * 8) * 32 + (s0 >> 4)) * 512 + lane * 8;
  const ushort *kb = K + ((long)(b * 8) * 32 + w * 8) * 512 + lane * 8;
  short8 bq = *(const short8 *)qb;  // head 0
  short8 ak[8];
#pragma unroll
  for (int jl = 0; jl < 8; ++jl) ak[jl] = *(const short8 *)(kb + jl * 512);

  float avgacc[8][4] = {};
#pragma unroll 1
  for (int h = 0; h < 8; ++h) {
    f32x4 acc[8];
    __builtin_amdgcn_s_setprio(1);
#pragma unroll
    for (int jl = 0; jl < 8; ++jl)
      acc[jl] = __builtin_amdgcn_mfma_f32_16x16x32_bf16(
          ak[jl], bq, (f32x4){0.f, 0.f, 0.f, 0.f}, 0, 0, 0);
    __builtin_amdgcn_s_setprio(0);
    __syncthreads();
#pragma unroll
    for (int jl = 0; jl < 8; ++jl) {
      const int ch = 32 * w + 4 * jl + quad;
      sc[l15 * 128 + (ch ^ (l15 & 7))] = acc[jl];
    }
    if (poker) ((float *)sc)[pokeIdx] = -1e30f;  // same-wave DS order
    __syncthreads();
    // prefetch next head's fragments; hidden under the solve
    if (h < 7) {
      bq = *(const short8 *)(qb + (h + 1) * 16384);
#pragma unroll
      for (int jl = 0; jl < 8; ++jl)
        ak[jl] = *(const short8 *)(kb + (h + 1) * 16384 + jl * 512);
    }
    f32x4 z[8];
#pragma unroll
    for (int c = 0; c < 8; ++c) z[c] = sc[rdbase + 16 * c];
    // top-3 scan: 4 independent 8-elem chains, then exact merges
    float q0a[4], q1a[4], q2a[4];
#pragma unroll
    for (int j = 0; j < 4; ++j) {
      float A0 = -3e38f, A1 = -3e38f, A2 = -3e38f;
#pragma unroll
      for (int c = 2 * j; c < 2 * j + 2; ++c)
#pragma unroll
        for (int r = 0; r < 4; ++r) {
          const float v = z[c][r];
          const float t1 = fminf(A0, v);
          A0 = fmaxf(A0, v);
          const float t2 = fminf(A1, t1);
          A1 = fmaxf(A1, t1);
          A2 = fmaxf(A2, t2);
        }
      q0a[j] = A0; q1a[j] = A1; q2a[j] = A2;
    }
    MERGE3(q0a[0], q1a[0], q2a[0], q0a[1], q1a[1], q2a[1]);
    MERGE3(q0a[2], q1a[2], q2a[2], q0a[3], q1a[3], q2a[3]);
    MERGE3(q0a[0], q1a[0], q2a[0], q0a[2], q1a[2], q2a[2]);
    const float q0 = q0a[0], q1 = q1a[0], q2 = q2a[0];
    const float M = dpp_max16(q0);
    const float thr = M - 1.0f;
    float tau = thr;
    float cOld = -1.f;
    if (__any(q2 > thr)) {
      // slow path: full scan, 4-way-split partial sums for ILP
#pragma unroll 1
      for (int it = 0; it < 32; ++it) {
        float ss[4] = {0.f, 0.f, 0.f, 0.f}, cc[4] = {0.f, 0.f, 0.f, 0.f};
#pragma unroll
        for (int j = 0; j < 4; ++j)
#pragma unroll
          for (int c = 2 * j; c < 2 * j + 2; ++c)
#pragma unroll
            for (int r = 0; r < 4; ++r) {
              const bool p = z[c][r] > tau;
              ss[j] += p ? z[c][r] : 0.f;
              cc[j] += p ? 1.f : 0.f;
            }
        float s = (ss[0] + ss[1]) + (ss[2] + ss[3]);
        float c = (cc[0] + cc[1]) + (cc[2] + cc[3]);
        s = dpp_sum16(s);
        c = dpp_sum16(c);
        const bool stable = (c == cOld);
        if (__all(stable)) break;
        if (!stable) {
          tau = (s - 1.f) / c;
          cOld = c;
        }
      }
    } else {
      // fast path: support per lane within {q0,q1}; tau monotone >= thr.
#pragma unroll 1
      for (int it = 0; it < 32; ++it) {
        const bool p0 = q0 > tau, p1 = q1 > tau;
        float s = (p0 ? q0 : 0.f) + (p1 ? q1 : 0.f);
        float c = (p0 ? 1.f : 0.f) + (p1 ? 1.f : 0.f);
        s = dpp_sum16(s);
        c = dpp_sum16(c);
        const bool stable = (c == cOld);
        if (__all(stable)) break;
        if (!stable) {
          tau = (s - 1.f) / c;
          cOld = c;
        }
      }
    }
#pragma unroll
    for (int c = 0; c < 8; ++c)
#pragma unroll
      for (int r = 0; r < 4; ++r)
        avgacc[c][r] += fmaxf(z[c][r] - tau, 0.f);
  }
  // avg write (fp32) + bf16 p-tile into first 16KB of LDS
  __syncthreads();
  ushort *pl = (ushort *)sc;
  float *dst = avg + ((b * 512 + sglob) << 9) + 4 * l15;
#pragma unroll
  for (int c = 0; c < 8; ++c) {
    float4 o;
    o.x = avgacc[c][0] * 0.125f;
    o.y = avgacc[c][1] * 0.125f;
    o.z = avgacc[c][2] * 0.125f;
    o.w = avgacc[c][3] * 0.125f;
    *(float4 *)(dst + 64 * c) = o;
    ushort4 pv;
    pv.x = f2bf(o.x); pv.y = f2bf(o.y); pv.z = f2bf(o.z); pv.w = f2bf(o.w);
    *(ushort4 *)((char *)pl +
                 ((myrow * 1024 + 128 * c + 8 * l15) ^ ((myrow & 7) << 4))) = pv;
  }
  __syncthreads();
  // out = avg . u : wave w covers e in [64w, 64w+64). U frag loads contiguous.
  const ushort *ubw = U + (long)b * 131072 + (long)(4 * w) * 16 * 512 + lane * 8;
  f32x4 oacc[4] = {{0.f, 0.f, 0.f, 0.f},
                   {0.f, 0.f, 0.f, 0.f},
                   {0.f, 0.f, 0.f, 0.f},
                   {0.f, 0.f, 0.f, 0.f}};
#pragma unroll
  for (int ks = 0; ks < 16; ++ks) {
    const short8 pf = *(const short8 *)(
        (char *)pl + (l15 * 1024 + ((ks * 64 + quad * 16) ^ ((l15 & 7) << 4))));
    __builtin_amdgcn_s_setprio(1);
#pragma unroll
    for (int nt = 0; nt < 4; ++nt) {
      const short8 uf = *(const short8 *)(ubw + (long)(nt * 16 + ks) * 512);
      oacc[nt] = __builtin_amdgcn_mfma_f32_16x16x32_bf16(uf, pf, oacc[nt], 0, 0, 0);
    }
    __builtin_amdgcn_s_setprio(0);
  }
  // stage out tile in second 16KB (disjoint from p-tile), then linear write
  char *obase = (char *)sc + 16384;
#pragma unroll
  for (int nt = 0; nt < 4; ++nt) {
    const int c4 = 16 * w + 4 * nt + quad;
    float4 st;
    st.x = oacc[nt][0]; st.y = oacc[nt][1];
    st.z = oacc[nt][2]; st.w = oacc[nt][3];
    *(float4 *)(obase + l15 * 1024 + ((c4 * 16) ^ ((l15 & 7) << 4))) = st;
  }
  __syncthreads();
  {
    const int row = tid >> 4, cb = tid & 15;
    float *og = out + ((long)b * 512 + s0 + row) * 256 + cb * 16;
#pragma unroll
    for (int k = 0; k < 4; ++k) {
      const float4 vv = *(const float4 *)(
          obase + row * 1024 + (((cb * 4 + k) * 16) ^ ((row & 7) << 4)));
      *(float4 *)(og + k * 4) = vv;
    }
  }
}

extern "C" void kernel_launch(void* const* d_in, const int* in_sizes, int n_in,
                              void* d_out, int out_size, void* d_ws, size_t ws_size,
                              hipStream_t stream) {
  const float *x  = (const float *)d_in[0];
  const float *Wq = (const float *)d_in[1];
  const float *bq = (const float *)d_in[2];
  const float *Wk = (const float *)d_in[3];
  const float *bk = (const float *)d_in[4];
  const float *Wv = (const float *)d_in[5];
  const float *bv = (const float *)d_in[6];
  const float *Wo = (const float *)d_in[7];
  const float *bo = (const float *)d_in[8];

  float *out = (float *)d_out;                 // [B,S,D]
  float *avg = out + 32 * 512 * 256;           // [B,S,S] fp32

  // ws (ushort units), all frag-chunk layouts:
  ushort *ws16 = (ushort *)d_ws;
  ushort *xbf = ws16;                          // 8192 chunks (16384x256)
  ushort *qbf = ws16 + 4194304;                // (b,h): 32 chunks (512x32)
  ushort *kbf = ws16 + 8388608;
  ushort *uT  = ws16 + 12582912;               // per b: 256 chunks (256x512)
  ushort *wbf = ws16 + 16777216;               // wqk 256 chunks | wvo 128
  float  *bvo = (float *)(ws16 + 16973824);    // [256] fp32

  prep<<<dim3(2368), dim3(256), 0, stream>>>(x, Wq, Wk, Wo, Wv, bv, bo, xbf,
                                             wbf, wbf + 131072, bvo);
  gemm_all<<<dim3(1024), dim3(256), 0, stream>>>(xbf, wbf, wbf + 131072, bq,
                                                 bk, bvo, qbf, kbf, uT);
  attn_sparsemax_fused<<<dim3(1024), dim3(256), 0, stream>>>(qbf, kbf, uT,
                                                             avg, out);
}